// Round 1
// baseline (1196.215 us; speedup 1.0000x reference)
//
#include <hip/hip_runtime.h>

typedef __bf16 bf16x8 __attribute__((ext_vector_type(8)));
typedef float  f32x4  __attribute__((ext_vector_type(4)));
typedef unsigned u32x4 __attribute__((ext_vector_type(4)));

#define WMAIN_DW (16*9*64*4)   /* 36864 dwords = 147456 B */
#define WPROJ_DW (8*64*4)      /*  2048 dwords =   8192 B */

__device__ __forceinline__ unsigned pk_bf16(float a, float b) {
  unsigned short ua = __builtin_bit_cast(unsigned short, (__bf16)a);
  unsigned short ub = __builtin_bit_cast(unsigned short, (__bf16)b);
  return (unsigned)ua | ((unsigned)ub << 16);
}

__device__ __forceinline__ float fast_tanh(float x) {
  // clamp so exp stays finite; tanh(9) == 1 to fp32
  x = fminf(9.f, fmaxf(-9.f, x));
  float e = __expf(2.f * x);
  return 1.f - 2.f * __builtin_amdgcn_rcpf(e + 1.f);
}

__global__ __launch_bounds__(1024) void rnn_fused(
    const float* __restrict__ inp, const float* __restrict__ hid,
    const float* __restrict__ Wih, const float* __restrict__ bih,
    const float* __restrict__ Whh, const float* __restrict__ bhh,
    const float* __restrict__ Wpr, const float* __restrict__ bpr,
    float* __restrict__ out, int Bn)
{
  // Packed-fragment bf16 weight images.
  // wmain frag (ct,ks): lane L holds A[c=16ct+(L&15)][k=32ks+8*(L>>4)+e], e=0..7
  //   ks<8  : W_hh columns 32ks..32ks+31
  //   ks==8 : k<24 -> W_ih, k==24 -> b_ih+b_hh (bias folded, X column == 1), else 0
  __shared__ __align__(16) unsigned wmain[WMAIN_DW];
  __shared__ __align__(16) unsigned wproj[WPROJ_DW];

  const int tid = threadIdx.x;

  for (int it = tid; it < WMAIN_DW; it += 1024) {
    int pair = it & 3;
    int ln   = (it >> 2) & 63;
    int frag = it >> 8;                 // ct*9 + ks
    int ct = frag / 9, ks = frag - ct * 9;
    int c  = ct * 16 + (ln & 15);
    int k0 = (ln >> 4) * 8 + pair * 2;
    float f0, f1;
    if (ks < 8) {
      const float* wr = Whh + c * 256 + ks * 32 + k0;
      f0 = wr[0]; f1 = wr[1];
    } else {
      int k1 = k0 + 1;
      f0 = (k0 < 24) ? Wih[c * 24 + k0] : ((k0 == 24) ? (bih[c] + bhh[c]) : 0.f);
      f1 = (k1 < 24) ? Wih[c * 24 + k1] : ((k1 == 24) ? (bih[c] + bhh[c]) : 0.f);
    }
    wmain[it] = pk_bf16(f0, f1);
  }
  for (int it = tid; it < WPROJ_DW; it += 1024) {
    int pair = it & 3;
    int ln   = (it >> 2) & 63;
    int cs   = it >> 8;
    int o    = ln & 15;
    int k    = cs * 32 + (ln >> 4) * 8 + pair * 2;
    float f0 = 0.f, f1 = 0.f;
    if (o < 12) { f0 = Wpr[o * 256 + k]; f1 = Wpr[o * 256 + k + 1]; }
    wproj[it] = pk_bf16(f0, f1);
  }
  __syncthreads();

  const int wave = tid >> 6;
  const int lane = tid & 63;
  const int g = lane >> 4, j = lane & 15;
  const bool ghi = (g >= 2);
  // proj rearrange source lanes (pull hp[2cs] / hp[2cs+1], select by g>>1)
  const int srcA = (((2 * g)     & 3) << 4) + j;
  const int srcB = (((2 * g + 1) & 3) << 4) + j;

  f32x4 bpj = {0.f, 0.f, 0.f, 0.f};
  if (g < 3) bpj = *(const f32x4*)(bpr + 4 * g);

  float* probs = out;
  float* hnew  = out + (size_t)Bn * 12;

  const bf16x8* wm = (const bf16x8*)wmain;
  const bf16x8* wp = (const bf16x8*)wproj;

  for (int q = 0; q < 4; ++q) {
    const int bt  = (blockIdx.x * 4 + q) * 16 + wave;  // 16-row tile id
    const int row = bt * 16 + j;
    const float* hrow = hid + (size_t)row * 256;

    f32x4 acc[16];
    #pragma unroll
    for (int ct = 0; ct < 16; ++ct) acc[ct] = (f32x4){0.f, 0.f, 0.f, 0.f};

    // ---- main GEMM: 8 hidden K-steps ----
    for (int ks = 0; ks < 8; ++ks) {
      f32x4 a = *(const f32x4*)(hrow + ks * 32 + g * 8);
      f32x4 b = *(const f32x4*)(hrow + ks * 32 + g * 8 + 4);
      bf16x8 xf;
      #pragma unroll
      for (int e = 0; e < 4; ++e) { xf[e] = (__bf16)a[e]; xf[4 + e] = (__bf16)b[e]; }
      #pragma unroll
      for (int ct = 0; ct < 16; ++ct)
        acc[ct] = __builtin_amdgcn_mfma_f32_16x16x32_bf16(
                      wm[(ct * 9 + ks) * 64 + lane], xf, acc[ct], 0, 0, 0);
    }
    // ---- input + bias K-step ----
    {
      bf16x8 xf;
      if (g < 3) {
        const float* irow = inp + (size_t)row * 24 + g * 8;
        f32x4 a = *(const f32x4*)irow;
        f32x4 b = *(const f32x4*)(irow + 4);
        #pragma unroll
        for (int e = 0; e < 4; ++e) { xf[e] = (__bf16)a[e]; xf[4 + e] = (__bf16)b[e]; }
      } else {
        #pragma unroll
        for (int e = 0; e < 8; ++e) xf[e] = (__bf16)0.f;
        xf[0] = (__bf16)1.f;   // k==24 bias column
      }
      #pragma unroll
      for (int ct = 0; ct < 16; ++ct)
        acc[ct] = __builtin_amdgcn_mfma_f32_16x16x32_bf16(
                      wm[(ct * 9 + 8) * 64 + lane], xf, acc[ct], 0, 0, 0);
    }

    // ---- tanh, store h_new (float4: 4 consecutive channels/lane), pack bf16 ----
    uint2 hp[16];
    float* hb = hnew + (size_t)row * 256 + 4 * g;
    #pragma unroll
    for (int ct = 0; ct < 16; ++ct) {
      float h0 = fast_tanh(acc[ct][0]);
      float h1 = fast_tanh(acc[ct][1]);
      float h2 = fast_tanh(acc[ct][2]);
      float h3 = fast_tanh(acc[ct][3]);
      f32x4 hv = {h0, h1, h2, h3};
      *(f32x4*)(hb + 16 * ct) = hv;
      hp[ct].x = pk_bf16(h0, h1);
      hp[ct].y = pk_bf16(h2, h3);
    }

    // ---- projection: rearrange h (D-layout) -> B-fragments via bpermute ----
    f32x4 pacc = {0.f, 0.f, 0.f, 0.f};
    #pragma unroll
    for (int cs = 0; cs < 8; ++cs) {
      unsigned a0 = (unsigned)__shfl((int)hp[2 * cs].x,     srcA, 64);
      unsigned a1 = (unsigned)__shfl((int)hp[2 * cs].y,     srcA, 64);
      unsigned b0 = (unsigned)__shfl((int)hp[2 * cs + 1].x, srcA, 64);
      unsigned b1 = (unsigned)__shfl((int)hp[2 * cs + 1].y, srcA, 64);
      unsigned a2 = (unsigned)__shfl((int)hp[2 * cs].x,     srcB, 64);
      unsigned a3 = (unsigned)__shfl((int)hp[2 * cs].y,     srcB, 64);
      unsigned b2 = (unsigned)__shfl((int)hp[2 * cs + 1].x, srcB, 64);
      unsigned b3 = (unsigned)__shfl((int)hp[2 * cs + 1].y, srcB, 64);
      u32x4 uu = { ghi ? b0 : a0, ghi ? b1 : a1, ghi ? b2 : a2, ghi ? b3 : a3 };
      bf16x8 xf = __builtin_bit_cast(bf16x8, uu);
      pacc = __builtin_amdgcn_mfma_f32_16x16x32_bf16(wp[cs * 64 + lane], xf, pacc, 0, 0, 0);
    }

    // ---- softmax over 12 outputs (o = 4g+r, reduce across g via shfl_xor) ----
    float l0 = (g < 3) ? pacc[0] + bpj[0] : -1e30f;
    float l1 = (g < 3) ? pacc[1] + bpj[1] : -1e30f;
    float l2 = (g < 3) ? pacc[2] + bpj[2] : -1e30f;
    float l3 = (g < 3) ? pacc[3] + bpj[3] : -1e30f;
    float m = fmaxf(fmaxf(l0, l1), fmaxf(l2, l3));
    m = fmaxf(m, __shfl_xor(m, 16, 64));
    m = fmaxf(m, __shfl_xor(m, 32, 64));
    float e0 = __expf(l0 - m), e1 = __expf(l1 - m);
    float e2 = __expf(l2 - m), e3 = __expf(l3 - m);
    float s = (e0 + e1) + (e2 + e3);
    s += __shfl_xor(s, 16, 64);
    s += __shfl_xor(s, 32, 64);
    float inv = __builtin_amdgcn_rcpf(s);   // s >= 1, safe
    if (g < 3) {
      f32x4 pv = {e0 * inv, e1 * inv, e2 * inv, e3 * inv};
      *(f32x4*)(probs + (size_t)row * 12 + 4 * g) = pv;
    }
  }
}

extern "C" void kernel_launch(void* const* d_in, const int* in_sizes, int n_in,
                              void* d_out, int out_size, void* d_ws, size_t ws_size,
                              hipStream_t stream) {
  const float* inp = (const float*)d_in[0];
  const float* hid = (const float*)d_in[1];
  const float* Wih = (const float*)d_in[2];
  const float* bih = (const float*)d_in[3];
  const float* Whh = (const float*)d_in[4];
  const float* bhh = (const float*)d_in[5];
  const float* Wpr = (const float*)d_in[6];
  const float* bpr = (const float*)d_in[7];

  int Bn = in_sizes[1] / 256;        // 262144
  int blocks = Bn / 1024;            // 256 blocks x 64 tiles x 16 rows
  rnn_fused<<<blocks, 1024, 0, stream>>>(inp, hid, Wih, bih, Whh, bhh,
                                         Wpr, bpr, (float*)d_out, Bn);
}